// Round 12
// baseline (355.149 us; speedup 1.0000x reference)
//
#include <hip/hip_runtime.h>
#include <cstddef>
#include <cstdint>

namespace {

typedef _Float16 f16x8 __attribute__((ext_vector_type(8)));
typedef float    f32x4 __attribute__((ext_vector_type(4)));

constexpr int kB = 4096, kT = 1024, kI = 8, kH = 12, kA = 4;
constexpr int kTC  = 16;              // timesteps per staged chunk
constexpr int kNCH = kT / kTC;        // 64 chunks
constexpr int kEPW = 16;              // elements per wave (= per block)
constexpr int kXF  = kTC * 16 * 4;    // uints per x-fragment buffer (1024)
constexpr int kHP  = 20;              // h-exchange row pad (floats, 16B-aligned reads, ~2-way banks)

constexpr float kL2E  = 1.442695041f;   // log2(e)
constexpr float kL2E2 = 2.885390082f;   // 2*log2(e)

__device__ __forceinline__ uint32_t pkrtz(float lo, float hi) {
    return __builtin_bit_cast(uint32_t, __builtin_amdgcn_cvt_pkrtz(lo, hi));
}
__device__ __forceinline__ float sigf(float s) {   // rcp(1+exp2(s)), scale pre-folded
    return __builtin_amdgcn_rcpf(1.0f + __builtin_amdgcn_exp2f(s));
}

__global__ __launch_bounds__(64, 1)
void lstm_mfma_kernel(const float* __restrict__ x,
                      const float* __restrict__ W_ih,
                      const float* __restrict__ W_hh,
                      const float* __restrict__ b_ih,
                      const float* __restrict__ b_hh,
                      const float* __restrict__ W_fc,
                      const float* __restrict__ b_fc,
                      float* __restrict__ out) {
    __shared__ uint32_t xf[2][kXF];     // x staged in B-fragment layout (f16 pairs)
    __shared__ float    hx[16 * kHP];   // h exchange: [elem][unit(12) pad->20]

    const int l   = threadIdx.x;        // single wave per block
    const int col = l & 15;             // element within wave
    const int hi  = l >> 4;             // fragment k-group / D-row group
    const int hw  = l >> 5;             // half-wave (staging)
    const int off = l & 31;             // offset within half-wave (staging)
    const int b0  = blockIdx.x * kEPW;
    const int b   = b0 + col;

    // ---- A fragments (weights) + bias C fragments ----
    // Block m row rr = 4*unit_local + gate (i,f,g,o). A: lane holds row=col, k=8*hi+j.
    // k<12: scl*W_hh[srow][k]; 12<=k<20: scl*W_ih[srow][k-12]; else 0. m=3: FC rows 0..3.
    f16x8 A[4];
    f32x4 Cb[4];
#pragma unroll
    for (int m = 0; m < 4; ++m) {
#pragma unroll
        for (int j = 0; j < 8; ++j) {
            const int k = 8 * hi + j;
            float v = 0.0f;
            if (m < 3) {
                const int u    = 4 * m + (col >> 2);
                const int g    = col & 3;
                const int srow = g * kH + u;
                const float scl = (g == 2) ? -kL2E2 : -kL2E;
                if (k < 12)      v = scl * W_hh[srow * kH + k];
                else if (k < 20) v = scl * W_ih[srow * kI + (k - 12)];
            } else {
                if (col < kA && k < 12) v = W_fc[col * kH + k];   // FC rows, unscaled
            }
            A[m][j] = (_Float16)v;
        }
#pragma unroll
        for (int r = 0; r < 4; ++r) {   // C/D row = 4*hi + r -> unit 4m+hi, gate r
            float bv = 0.0f;
            if (m < 3) {
                const int srow = r * kH + (4 * m + hi);
                const float scl = (r == 2) ? -kL2E2 : -kL2E;
                bv = scl * (b_ih[srow] + b_hh[srow]);
            } else if (hi == 0) {
                bv = b_fc[r];
            }
            Cb[m][r] = bv;
        }
    }

    // ---- prologue: zero h-exchange, stage chunk 0 ----
    hx[col * kHP + hi]     = 0.0f;
    hx[col * kHP + 4 + hi] = 0.0f;
    hx[col * kHP + 8 + hi] = 0.0f;
    {
        // coalesced: half-wave hw covers element e=2r+hw, 32 lanes span the 512B chunk
#pragma unroll
        for (int r = 0; r < 8; ++r) {
            const int e = 2 * r + hw;
            const float4 v = ((const float4*)(x + ((size_t)(b0 + e) * kT) * kI))[off];
            const int tloc = off >> 1, half = off & 1;
            uint2 u; u.x = pkrtz(v.x, v.y); u.y = pkrtz(v.z, v.w);
            *(uint2*)&xf[0][(tloc * 16 + e) * 4 + half * 2] = u;
        }
    }
    asm volatile("s_waitcnt lgkmcnt(0)" ::: "memory");
    __builtin_amdgcn_sched_barrier(0);

    float c0 = 0.0f, c1 = 0.0f, c2 = 0.0f;
    float h0 = 0.0f, h1 = 0.0f, h2 = 0.0f;
    float* opp = out + ((size_t)b * kT - 1) * kA;   // store target for out[t-1]

    const int hb   = col * kHP;
    const int ha0  = hb + ((hi == 0) ? 0 : 8);
    const int ha1  = hb + ((hi == 0) ? 4 : 8);
    const int xoff = (hi == 2) ? 2 : 0;

    int cb = 0;
#pragma unroll 1
    for (int ch = 0; ch < kNCH; ++ch) {
        float4 rv[8];
        if (ch + 1 < kNCH) {   // issue next chunk's global loads early
#pragma unroll
            for (int r = 0; r < 8; ++r) {
                const int e = 2 * r + hw;
                rv[r] = ((const float4*)(x + ((size_t)(b0 + e) * kT + (ch + 1) * kTC) * kI))[off];
            }
        }
#pragma unroll 2
        for (int tt = 0; tt < kTC; ++tt) {
            const int t = ch * kTC + tt;
            // ---- build B = [h(12) | x(8) | 0(12)] fragment (k = 8*hi + j) ----
            const f32x4 hr0 = *(const f32x4*)&hx[ha0];
            const f32x4 hr1 = *(const f32x4*)&hx[ha1];
            const uint2 xr  = *(const uint2*)&xf[cb][(tt * 16 + col) * 4 + xoff];
            const uint32_t p0 = pkrtz(hr0[0], hr0[1]);
            const uint32_t p1 = pkrtz(hr0[2], hr0[3]);
            const uint32_t p2 = pkrtz(hr1[0], hr1[1]);
            const uint32_t p3 = pkrtz(hr1[2], hr1[3]);
            uint4 Bu;
            Bu.x = (hi < 2) ? p0 : ((hi == 2) ? xr.x : 0u);
            Bu.y = (hi < 2) ? p1 : ((hi == 2) ? xr.y : 0u);
            Bu.z = (hi == 0) ? p2 : ((hi == 1) ? xr.x : 0u);
            Bu.w = (hi == 0) ? p3 : ((hi == 1) ? xr.y : 0u);
            const f16x8 Bf = __builtin_bit_cast(f16x8, Bu);
            // ---- 4 MFMAs: gate pre-acts (scaled) + FC(h_{t-1}) ----
            const f32x4 d0 = __builtin_amdgcn_mfma_f32_16x16x32_f16(A[0], Bf, Cb[0], 0, 0, 0);
            const f32x4 d1 = __builtin_amdgcn_mfma_f32_16x16x32_f16(A[1], Bf, Cb[1], 0, 0, 0);
            const f32x4 d2 = __builtin_amdgcn_mfma_f32_16x16x32_f16(A[2], Bf, Cb[2], 0, 0, 0);
            const f32x4 d3 = __builtin_amdgcn_mfma_f32_16x16x32_f16(A[3], Bf, Cb[3], 0, 0, 0);
            // FC: d3 rows 0..3 (lanes hi==0) = out[t-1]
            if (t != 0 && hi == 0) {
                float4 fo; fo.x = d3[0]; fo.y = d3[1]; fo.z = d3[2]; fo.w = d3[3];
                *(float4*)(opp + (size_t)t * kA) = fo;
            }
            // ---- activations + state update (unit 4m+hi of element col) ----
            {
                const float iv = sigf(d0[0]);
                const float fv = sigf(d0[1]);
                const float gv = fmaf(2.0f, sigf(d0[2]), -1.0f);
                const float ov = sigf(d0[3]);
                c0 = fmaf(fv, c0, iv * gv);
                h0 = ov * fmaf(2.0f, sigf(-kL2E2 * c0), -1.0f);
            }
            {
                const float iv = sigf(d1[0]);
                const float fv = sigf(d1[1]);
                const float gv = fmaf(2.0f, sigf(d1[2]), -1.0f);
                const float ov = sigf(d1[3]);
                c1 = fmaf(fv, c1, iv * gv);
                h1 = ov * fmaf(2.0f, sigf(-kL2E2 * c1), -1.0f);
            }
            {
                const float iv = sigf(d2[0]);
                const float fv = sigf(d2[1]);
                const float gv = fmaf(2.0f, sigf(d2[2]), -1.0f);
                const float ov = sigf(d2[3]);
                c2 = fmaf(fv, c2, iv * gv);
                h2 = ov * fmaf(2.0f, sigf(-kL2E2 * c2), -1.0f);
            }
            // ---- publish h_t (units 4m+hi of element col) + fence ----
            hx[hb + hi]     = h0;
            hx[hb + 4 + hi] = h1;
            hx[hb + 8 + hi] = h2;
            asm volatile("s_waitcnt lgkmcnt(0)" ::: "memory");
            __builtin_amdgcn_sched_barrier(0);
        }
        if (ch + 1 < kNCH) {   // late LDS write of prefetched chunk + fence
            const int nb = cb ^ 1;
#pragma unroll
            for (int r = 0; r < 8; ++r) {
                const int e = 2 * r + hw;
                const int tloc = off >> 1, half = off & 1;
                uint2 u; u.x = pkrtz(rv[r].x, rv[r].y); u.y = pkrtz(rv[r].z, rv[r].w);
                *(uint2*)&xf[nb][(tloc * 16 + e) * 4 + half * 2] = u;
            }
            asm volatile("s_waitcnt lgkmcnt(0)" ::: "memory");
            __builtin_amdgcn_sched_barrier(0);
            cb = nb;
        }
    }

    {   // epilogue: out[T-1] = FC(h_{T-1}) via one more m=3 MFMA (x-slots zero)
        const f32x4 hr0 = *(const f32x4*)&hx[ha0];
        const f32x4 hr1 = *(const f32x4*)&hx[ha1];
        const uint32_t p0 = pkrtz(hr0[0], hr0[1]);
        const uint32_t p1 = pkrtz(hr0[2], hr0[3]);
        const uint32_t p2 = pkrtz(hr1[0], hr1[1]);
        const uint32_t p3 = pkrtz(hr1[2], hr1[3]);
        uint4 Bu;
        Bu.x = (hi < 2) ? p0 : 0u;
        Bu.y = (hi < 2) ? p1 : 0u;
        Bu.z = (hi == 0) ? p2 : 0u;
        Bu.w = (hi == 0) ? p3 : 0u;
        const f16x8 Bf = __builtin_bit_cast(f16x8, Bu);
        const f32x4 d3 = __builtin_amdgcn_mfma_f32_16x16x32_f16(A[3], Bf, Cb[3], 0, 0, 0);
        if (hi == 0) {
            float4 fo; fo.x = d3[0]; fo.y = d3[1]; fo.z = d3[2]; fo.w = d3[3];
            *(float4*)(opp + (size_t)kT * kA) = fo;
        }
    }
    {   // hn, cn: lane holds units 4m+hi of element col (fp32 master state)
        float* hn = out + (size_t)kB * kT * kA;
        hn[(size_t)b * kH + hi]     = h0;
        hn[(size_t)b * kH + 4 + hi] = h1;
        hn[(size_t)b * kH + 8 + hi] = h2;
        float* cn = hn + (size_t)kB * kH;
        cn[(size_t)b * kH + hi]     = c0;
        cn[(size_t)b * kH + 4 + hi] = c1;
        cn[(size_t)b * kH + 8 + hi] = c2;
    }
}

}  // namespace

extern "C" void kernel_launch(void* const* d_in, const int* in_sizes, int n_in,
                              void* d_out, int out_size, void* d_ws, size_t ws_size,
                              hipStream_t stream) {
    (void)in_sizes; (void)n_in; (void)d_ws; (void)ws_size; (void)out_size;
    const float* x    = (const float*)d_in[0];
    const float* W_ih = (const float*)d_in[1];
    const float* W_hh = (const float*)d_in[2];
    const float* b_ih = (const float*)d_in[3];
    const float* b_hh = (const float*)d_in[4];
    const float* W_fc = (const float*)d_in[5];
    const float* b_fc = (const float*)d_in[6];
    float* out = (float*)d_out;
    hipLaunchKernelGGL(lstm_mfma_kernel, dim3(kB / kEPW), dim3(64), 0, stream,
                       x, W_ih, W_hh, b_ih, b_hh, W_fc, b_fc, out);
}

// Round 13
// 298.886 us; speedup vs baseline: 1.1882x; 1.1882x over previous
//
#include <hip/hip_runtime.h>
#include <cstddef>
#include <cstdint>

namespace {

typedef __fp16 h2v __attribute__((ext_vector_type(2)));

constexpr int kB = 4096, kT = 1024, kI = 8, kH = 12, kA = 4;
constexpr int kTC  = 32;               // timesteps per staged chunk
constexpr int kNCH = kT / kTC;         // 32 chunks
constexpr int kXRegU = 132;            // 128 payload uints + 4 pad per element region
constexpr int kBlkU  = 16 * kXRegU;    // 16 elements per block

constexpr float kL2E  = 1.442695041f;   // log2(e)
constexpr float kL2E2 = 2.885390082f;   // 2*log2(e)

template<int N>
__device__ __forceinline__ uint32_t ror16u(uint32_t v) {
    return (uint32_t)__builtin_amdgcn_mov_dpp((int)v, 0x120 + N, 0xF, 0xF, false);
}
__device__ __forceinline__ float ror16f1(float v) {
    return __int_as_float(__builtin_amdgcn_mov_dpp(__float_as_int(v), 0x121, 0xF, 0xF, false));
}
__device__ __forceinline__ uint32_t pkrtz(float lo, float hi) {
    return __builtin_bit_cast(uint32_t, __builtin_amdgcn_cvt_pkrtz(lo, hi));
}
__device__ __forceinline__ h2v uh(uint32_t u) { return __builtin_bit_cast(h2v, u); }
__device__ __forceinline__ float fd2(h2v w, h2v v, float acc) {
    return __builtin_amdgcn_fdot2(w, v, acc, false);
}
__device__ __forceinline__ float sigf(float s) {   // rcp(1+exp2(s)), scale pre-folded
    return __builtin_amdgcn_rcpf(1.0f + __builtin_amdgcn_exp2f(s));
}

__global__ __launch_bounds__(256, 1)
void lstm_fused_kernel(const float* __restrict__ x,
                       const float* __restrict__ W_ih,
                       const float* __restrict__ W_hh,
                       const float* __restrict__ b_ih,
                       const float* __restrict__ b_hh,
                       const float* __restrict__ W_fc,
                       const float* __restrict__ b_fc,
                       float* __restrict__ out) {
    __shared__ uint32_t xs[2][kBlkU];   // staged x (f16 pairs), double-buffered, wave-private

    const int tid = threadIdx.x;
    const int wv  = tid >> 6;           // wave in block
    const int l64 = tid & 63;           // lane in wave
    const int grp = l64 >> 4;           // 16-lane group == DPP row == element
    const int r   = l64 & 15;           // unit index within element (12..15 = FC rows)
    const int ei  = wv * 4 + grp;       // element index within block
    const int b   = blockIdx.x * 16 + ei;
    const bool isFC = (r >= kH);
    const int a   = isFC ? (r - kH) : 0;

    // DPP row_ror direction probe (r5..r11-proven)
    const int probe = __builtin_amdgcn_mov_dpp(r, 0x121, 0xF, 0xF, false);
    const int dir   = (probe - r) & 15;

    // ---- packed f16 weights, all 4 gates per lane; h-cols pre-rotated & paired ----
    h2v wp[4][8], xp[4][4];
    float bs[4];
    if (!isFC) {
#pragma unroll
        for (int g = 0; g < 4; ++g) {              // PyTorch gate order i,f,g,o
            const int row = g * kH + r;
            const float scl = (g == 2) ? -kL2E2 : -kL2E;   // tanh row gets 2*log2e
#pragma unroll
            for (int jj = 0; jj < 8; ++jj) {
                const int c0 = (r + dir * 2 * jj) & 15;
                const int c1 = (c0 + dir) & 15;
                const float u0 = (c0 < kH) ? W_hh[row * kH + c0] : 0.0f;
                const float u1 = (c1 < kH) ? W_hh[row * kH + c1] : 0.0f;
                wp[g][jj] = h2v{(__fp16)(scl * u0), (__fp16)(scl * u1)};
            }
#pragma unroll
            for (int i2 = 0; i2 < 4; ++i2)
                xp[g][i2] = h2v{(__fp16)(scl * W_ih[row * kI + 2 * i2]),
                                (__fp16)(scl * W_ih[row * kI + 2 * i2 + 1])};
            bs[g] = scl * (b_ih[row] + b_hh[row]);
        }
    } else {   // FC lane: gate0 = W_fc row (unscaled); gates 1-3 all-zero
#pragma unroll
        for (int jj = 0; jj < 8; ++jj) {
            const int c0 = (r + dir * 2 * jj) & 15;
            const int c1 = (c0 + dir) & 15;
            const float u0 = (c0 < kH) ? W_fc[a * kH + c0] : 0.0f;
            const float u1 = (c1 < kH) ? W_fc[a * kH + c1] : 0.0f;
            wp[0][jj] = h2v{(__fp16)u0, (__fp16)u1};
            wp[1][jj] = h2v{(__fp16)0.f, (__fp16)0.f};
            wp[2][jj] = wp[1][jj];
            wp[3][jj] = wp[1][jj];
        }
#pragma unroll
        for (int i2 = 0; i2 < 4; ++i2) {
            xp[0][i2] = h2v{(__fp16)0.f, (__fp16)0.f};
            xp[1][i2] = xp[0][i2]; xp[2][i2] = xp[0][i2]; xp[3][i2] = xp[0][i2];
        }
        bs[0] = b_fc[a]; bs[1] = 0.0f; bs[2] = 0.0f; bs[3] = 0.0f;
        // f=sig(0)=0.5, g=0, o=0.5 -> c,h stay EXACTLY 0 on FC lanes (r11-proven)
    }

    // ---- x staging: each group stages its own element (f32 global -> f16 LDS) ----
    const float* xg = x + (size_t)b * (kT * kI);
    const int reg = ei * kXRegU;

    float4 rv0, rv1, rv2, rv3;
    {   // prologue: chunk 0 -> buffer 0
        const float4* gp = (const float4*)xg;
        rv0 = gp[r]; rv1 = gp[16 + r]; rv2 = gp[32 + r]; rv3 = gp[48 + r];
        uint2 u;
        u.x = pkrtz(rv0.x, rv0.y); u.y = pkrtz(rv0.z, rv0.w);
        *(uint2*)&xs[0][reg + 2 * r] = u;
        u.x = pkrtz(rv1.x, rv1.y); u.y = pkrtz(rv1.z, rv1.w);
        *(uint2*)&xs[0][reg + 32 + 2 * r] = u;
        u.x = pkrtz(rv2.x, rv2.y); u.y = pkrtz(rv2.z, rv2.w);
        *(uint2*)&xs[0][reg + 64 + 2 * r] = u;
        u.x = pkrtz(rv3.x, rv3.y); u.y = pkrtz(rv3.z, rv3.w);
        *(uint2*)&xs[0][reg + 96 + 2 * r] = u;
    }
    asm volatile("s_waitcnt lgkmcnt(0)" ::: "memory");
    __builtin_amdgcn_sched_barrier(0);

    float h = 0.0f, c = 0.0f;
    uint32_t hrp[8];
#pragma unroll
    for (int k = 0; k < 8; ++k) hrp[k] = 0u;

    // xq_g = bias + x-dot for the UPCOMING step (software-pipelined x-part)
    float xq0, xq1, xq2, xq3;
    {
        const uint4 x0 = *(const uint4*)&xs[0][reg];
        const h2v v0 = uh(x0.x), v1 = uh(x0.y), v2 = uh(x0.z), v3 = uh(x0.w);
        xq0 = fd2(xp[0][3], v3, fd2(xp[0][2], v2, fd2(xp[0][1], v1, fd2(xp[0][0], v0, bs[0]))));
        xq1 = fd2(xp[1][3], v3, fd2(xp[1][2], v2, fd2(xp[1][1], v1, fd2(xp[1][0], v0, bs[1]))));
        xq2 = fd2(xp[2][3], v3, fd2(xp[2][2], v2, fd2(xp[2][1], v1, fd2(xp[2][0], v0, bs[2]))));
        xq3 = fd2(xp[3][3], v3, fd2(xp[3][2], v2, fd2(xp[3][1], v1, fd2(xp[3][0], v0, bs[3]))));
    }

    float* op = out + (size_t)b * (kT * kA) + a;

    int cb = 0;
#pragma unroll 1
    for (int ch = 0; ch < kNCH; ++ch) {
        if (ch + 1 < kNCH) {   // issue next chunk's global loads early
            const float4* gp = (const float4*)(xg + (size_t)(ch + 1) * (kTC * kI));
            rv0 = gp[r]; rv1 = gp[16 + r]; rv2 = gp[32 + r]; rv3 = gp[48 + r];
        }
#pragma unroll 2
        for (int tt = 0; tt < kTC; ++tt) {
            // prefetch x(t+1) fragment (consumed mid-step for xpart(t+1))
            uint4 xn;
            if (tt + 1 < kTC) xn = *(const uint4*)&xs[cb][reg + (tt + 1) * 4];
            // gate pre-acts: per gate, two 4-deep fdot2 chains (A from xpart, B from 0)
            float a0 = xq0, a1 = xq1, a2 = xq2, a3 = xq3;
            float e0, e1, e2, e3;
            {
                const h2v h4 = uh(hrp[4]);
                e0 = fd2(wp[0][4], h4, 0.0f);
                e1 = fd2(wp[1][4], h4, 0.0f);
                e2 = fd2(wp[2][4], h4, 0.0f);
                e3 = fd2(wp[3][4], h4, 0.0f);
            }
#pragma unroll
            for (int jj = 0; jj < 4; ++jj) {
                const h2v hv = uh(hrp[jj]);
                a0 = fd2(wp[0][jj], hv, a0);
                a1 = fd2(wp[1][jj], hv, a1);
                a2 = fd2(wp[2][jj], hv, a2);
                a3 = fd2(wp[3][jj], hv, a3);
            }
#pragma unroll
            for (int jj = 5; jj < 8; ++jj) {
                const h2v hv = uh(hrp[jj]);
                e0 = fd2(wp[0][jj], hv, e0);
                e1 = fd2(wp[1][jj], hv, e1);
                e2 = fd2(wp[2][jj], hv, e2);
                e3 = fd2(wp[3][jj], hv, e3);
            }
            const float s0 = a0 + e0;
            const float s1 = a1 + e1;
            const float s2 = a2 + e2;
            const float s3 = a3 + e3;
            // FC lanes: s0 = wfc.h_{t-1} + b_fc = out[t-1] (delayed store)
            if ((ch | tt) != 0) { if (isFC) op[-kA] = s0; }
            // activations (scales pre-folded)
            const float iv = sigf(s0);
            const float fv = sigf(s1);
            const float gv = fmaf(2.0f, sigf(s2), -1.0f);
            const float ov = sigf(s3);
            // xpart(t+1): independent of h_t -> fills the trans/c-chain stall window
            float n0, n1, n2, n3;
            if (tt + 1 < kTC) {
                const h2v v0 = uh(xn.x), v1 = uh(xn.y), v2 = uh(xn.z), v3 = uh(xn.w);
                n0 = fd2(xp[0][3], v3, fd2(xp[0][2], v2, fd2(xp[0][1], v1, fd2(xp[0][0], v0, bs[0]))));
                n1 = fd2(xp[1][3], v3, fd2(xp[1][2], v2, fd2(xp[1][1], v1, fd2(xp[1][0], v0, bs[1]))));
                n2 = fd2(xp[2][3], v3, fd2(xp[2][2], v2, fd2(xp[2][1], v1, fd2(xp[2][0], v0, bs[2]))));
                n3 = fd2(xp[3][3], v3, fd2(xp[3][2], v2, fd2(xp[3][1], v1, fd2(xp[3][0], v0, bs[3]))));
            }
            // state update — fully in-lane
            c = fmaf(fv, c, iv * gv);
            const float tc = fmaf(2.0f, sigf(-kL2E2 * c), -1.0f);
            h = ov * tc;
            // packed h broadcast: Q = (h_r, h_{r+dir}); one DPP rotate = two h values
            const float hn1 = ror16f1(h);
            const uint32_t Q = pkrtz(h, hn1);
            hrp[0] = Q;
            hrp[1] = ror16u<2>(Q);
            hrp[2] = ror16u<4>(Q);
            hrp[3] = ror16u<6>(Q);
            hrp[4] = ror16u<8>(Q);
            hrp[5] = ror16u<10>(Q);
            hrp[6] = ror16u<12>(Q);
            hrp[7] = ror16u<14>(Q);
            if (tt + 1 < kTC) { xq0 = n0; xq1 = n1; xq2 = n2; xq3 = n3; }
            op += kA;
        }
        if (ch + 1 < kNCH) {   // late LDS write of prefetched chunk + fence
            const int nb = cb ^ 1;
            uint2 u;
            u.x = pkrtz(rv0.x, rv0.y); u.y = pkrtz(rv0.z, rv0.w);
            *(uint2*)&xs[nb][reg + 2 * r] = u;
            u.x = pkrtz(rv1.x, rv1.y); u.y = pkrtz(rv1.z, rv1.w);
            *(uint2*)&xs[nb][reg + 32 + 2 * r] = u;
            u.x = pkrtz(rv2.x, rv2.y); u.y = pkrtz(rv2.z, rv2.w);
            *(uint2*)&xs[nb][reg + 64 + 2 * r] = u;
            u.x = pkrtz(rv3.x, rv3.y); u.y = pkrtz(rv3.z, rv3.w);
            *(uint2*)&xs[nb][reg + 96 + 2 * r] = u;
            asm volatile("s_waitcnt lgkmcnt(0)" ::: "memory");
            __builtin_amdgcn_sched_barrier(0);
            {   // xpart for first step of next chunk
                const uint4 x0 = *(const uint4*)&xs[nb][reg];
                const h2v v0 = uh(x0.x), v1 = uh(x0.y), v2 = uh(x0.z), v3 = uh(x0.w);
                xq0 = fd2(xp[0][3], v3, fd2(xp[0][2], v2, fd2(xp[0][1], v1, fd2(xp[0][0], v0, bs[0]))));
                xq1 = fd2(xp[1][3], v3, fd2(xp[1][2], v2, fd2(xp[1][1], v1, fd2(xp[1][0], v0, bs[1]))));
                xq2 = fd2(xp[2][3], v3, fd2(xp[2][2], v2, fd2(xp[2][1], v1, fd2(xp[2][0], v0, bs[2]))));
                xq3 = fd2(xp[3][3], v3, fd2(xp[3][2], v2, fd2(xp[3][1], v1, fd2(xp[3][0], v0, bs[3]))));
            }
            cb = nb;
        }
    }

    {   // epilogue: out[T-1] = wfc . h_{T-1} + b_fc (full 8-pair h-dot)
        float s0 = bs[0];
#pragma unroll
        for (int jj = 0; jj < 8; ++jj)
            s0 = fd2(wp[0][jj], uh(hrp[jj]), s0);
        if (isFC) op[-kA] = s0;
    }
    if (!isFC) {   // hn, cn (fp32 master state), concatenated after out
        float* hn = out + (size_t)kB * kT * kA;
        hn[(size_t)b * kH + r] = h;
        hn[(size_t)kB * kH + (size_t)b * kH + r] = c;
    }
}

}  // namespace

extern "C" void kernel_launch(void* const* d_in, const int* in_sizes, int n_in,
                              void* d_out, int out_size, void* d_ws, size_t ws_size,
                              hipStream_t stream) {
    (void)in_sizes; (void)n_in; (void)d_ws; (void)ws_size; (void)out_size;
    const float* x    = (const float*)d_in[0];
    const float* W_ih = (const float*)d_in[1];
    const float* W_hh = (const float*)d_in[2];
    const float* b_ih = (const float*)d_in[3];
    const float* b_hh = (const float*)d_in[4];
    const float* W_fc = (const float*)d_in[5];
    const float* b_fc = (const float*)d_in[6];
    float* out = (float*)d_out;
    hipLaunchKernelGGL(lstm_fused_kernel, dim3(kB / 16), dim3(256), 0, stream,
                       x, W_ih, W_hh, b_ih, b_hh, W_fc, b_fc, out);
}

// Round 14
// 265.422 us; speedup vs baseline: 1.3381x; 1.1261x over previous
//
#include <hip/hip_runtime.h>
#include <cstddef>
#include <cstdint>

namespace {

typedef __fp16 h2v __attribute__((ext_vector_type(2)));

constexpr int kB = 4096, kT = 1024, kI = 8, kH = 12, kA = 4;
constexpr int kTC  = 16;               // timesteps per staged chunk (32->16: halve rv live range)
constexpr int kNCH = kT / kTC;         // 64 chunks
constexpr int kXRegU = 68;             // 64 payload uints + 4 pad per element region
constexpr int kBlkU  = 16 * kXRegU;    // 16 elements per block

constexpr float kL2E  = 1.442695041f;   // log2(e)
constexpr float kL2E2 = 2.885390082f;   // 2*log2(e)

template<int N>
__device__ __forceinline__ uint32_t ror16u(uint32_t v) {
    return (uint32_t)__builtin_amdgcn_mov_dpp((int)v, 0x120 + N, 0xF, 0xF, false);
}
__device__ __forceinline__ float ror16f1(float v) {
    return __int_as_float(__builtin_amdgcn_mov_dpp(__float_as_int(v), 0x121, 0xF, 0xF, false));
}
__device__ __forceinline__ uint32_t pkrtz(float lo, float hi) {
    return __builtin_bit_cast(uint32_t, __builtin_amdgcn_cvt_pkrtz(lo, hi));
}
__device__ __forceinline__ h2v uh(uint32_t u) { return __builtin_bit_cast(h2v, u); }
__device__ __forceinline__ float fd2(h2v w, h2v v, float acc) {
    return __builtin_amdgcn_fdot2(w, v, acc, false);
}
__device__ __forceinline__ float sigf(float s) {   // rcp(1+exp2(s)), scale pre-folded
    return __builtin_amdgcn_rcpf(1.0f + __builtin_amdgcn_exp2f(s));
}

__global__ __launch_bounds__(256, 1)
void lstm_fused_kernel(const float* __restrict__ x,
                       const float* __restrict__ W_ih,
                       const float* __restrict__ W_hh,
                       const float* __restrict__ b_ih,
                       const float* __restrict__ b_hh,
                       const float* __restrict__ W_fc,
                       const float* __restrict__ b_fc,
                       float* __restrict__ out) {
    __shared__ uint32_t xs[2][kBlkU];   // staged x (f16 pairs), double-buffered, wave-private

    const int tid = threadIdx.x;
    const int wv  = tid >> 6;           // wave in block
    const int l64 = tid & 63;           // lane in wave
    const int grp = l64 >> 4;           // 16-lane group == DPP row == element
    const int r   = l64 & 15;           // unit index within element (12..15 = FC rows)
    const int ei  = wv * 4 + grp;       // element index within block
    const int b   = blockIdx.x * 16 + ei;
    const bool isFC = (r >= kH);
    const int a   = isFC ? (r - kH) : 0;

    // DPP row_ror direction probe (r5..r11-proven)
    const int probe = __builtin_amdgcn_mov_dpp(r, 0x121, 0xF, 0xF, false);
    const int dir   = (probe - r) & 15;

    // ---- packed f16 weights, all 4 gates per lane; h-cols pre-rotated & paired ----
    h2v wp[4][8], xp[4][4];
    float bs[4];
    if (!isFC) {
#pragma unroll
        for (int g = 0; g < 4; ++g) {              // PyTorch gate order i,f,g,o
            const int row = g * kH + r;
            const float scl = (g == 2) ? -kL2E2 : -kL2E;   // tanh row gets 2*log2e
#pragma unroll
            for (int jj = 0; jj < 8; ++jj) {
                const int c0 = (r + dir * 2 * jj) & 15;
                const int c1 = (c0 + dir) & 15;
                const float u0 = (c0 < kH) ? W_hh[row * kH + c0] : 0.0f;
                const float u1 = (c1 < kH) ? W_hh[row * kH + c1] : 0.0f;
                wp[g][jj] = h2v{(__fp16)(scl * u0), (__fp16)(scl * u1)};
            }
#pragma unroll
            for (int i2 = 0; i2 < 4; ++i2)
                xp[g][i2] = h2v{(__fp16)(scl * W_ih[row * kI + 2 * i2]),
                                (__fp16)(scl * W_ih[row * kI + 2 * i2 + 1])};
            bs[g] = scl * (b_ih[row] + b_hh[row]);
        }
    } else {   // FC lane: gate0 = W_fc row (unscaled); gates 1-3 all-zero
#pragma unroll
        for (int jj = 0; jj < 8; ++jj) {
            const int c0 = (r + dir * 2 * jj) & 15;
            const int c1 = (c0 + dir) & 15;
            const float u0 = (c0 < kH) ? W_fc[a * kH + c0] : 0.0f;
            const float u1 = (c1 < kH) ? W_fc[a * kH + c1] : 0.0f;
            wp[0][jj] = h2v{(__fp16)u0, (__fp16)u1};
            wp[1][jj] = h2v{(__fp16)0.f, (__fp16)0.f};
            wp[2][jj] = wp[1][jj];
            wp[3][jj] = wp[1][jj];
        }
#pragma unroll
        for (int i2 = 0; i2 < 4; ++i2) {
            xp[0][i2] = h2v{(__fp16)0.f, (__fp16)0.f};
            xp[1][i2] = xp[0][i2]; xp[2][i2] = xp[0][i2]; xp[3][i2] = xp[0][i2];
        }
        bs[0] = b_fc[a]; bs[1] = 0.0f; bs[2] = 0.0f; bs[3] = 0.0f;
        // f=sig(0)=0.5, g=0, o=0.5 -> c,h stay EXACTLY 0 on FC lanes (r11-proven)
    }

    // ---- x staging: each group stages its own element (f32 global -> f16 LDS) ----
    const float* xg = x + (size_t)b * (kT * kI);
    const int reg = ei * kXRegU;

    float4 rv0, rv1;
    {   // prologue: chunk 0 -> buffer 0 (16 steps = 128 floats = 2 float4/lane)
        const float4* gp = (const float4*)xg;
        rv0 = gp[r]; rv1 = gp[16 + r];
        uint2 u;
        u.x = pkrtz(rv0.x, rv0.y); u.y = pkrtz(rv0.z, rv0.w);
        *(uint2*)&xs[0][reg + 2 * r] = u;
        u.x = pkrtz(rv1.x, rv1.y); u.y = pkrtz(rv1.z, rv1.w);
        *(uint2*)&xs[0][reg + 32 + 2 * r] = u;
    }
    asm volatile("s_waitcnt lgkmcnt(0)" ::: "memory");
    __builtin_amdgcn_sched_barrier(0);

    float h = 0.0f, c = 0.0f;
    uint32_t hrp[8];
#pragma unroll
    for (int k = 0; k < 8; ++k) hrp[k] = 0u;

    uint4 xr = *(const uint4*)&xs[0][reg];   // step 0: 8 f16

    float* op = out + (size_t)b * (kT * kA) + a;

    int cb = 0;
#pragma unroll 1
    for (int ch = 0; ch < kNCH; ++ch) {
        if (ch + 1 < kNCH) {   // issue next chunk's global loads early
            const float4* gp = (const float4*)(xg + (size_t)(ch + 1) * (kTC * kI));
            rv0 = gp[r]; rv1 = gp[16 + r];
        }
#pragma unroll 2
        for (int tt = 0; tt < kTC; ++tt) {
            // prefetch next step's x FIRST (max slack before use)
            uint4 xrn;
            if (tt + 1 < kTC) xrn = *(const uint4*)&xs[cb][reg + (tt + 1) * 4];
            // 4 gate dots: 32 fdot2 over paired h + 16 over x (fp32 accum)
            float s0 = bs[0], s1 = bs[1], s2 = bs[2], s3 = bs[3];
#pragma unroll
            for (int jj = 0; jj < 8; ++jj) {
                const h2v hv = uh(hrp[jj]);
                s0 = fd2(wp[0][jj], hv, s0);
                s1 = fd2(wp[1][jj], hv, s1);
                s2 = fd2(wp[2][jj], hv, s2);
                s3 = fd2(wp[3][jj], hv, s3);
            }
            {
                const h2v xv0 = uh(xr.x), xv1 = uh(xr.y), xv2 = uh(xr.z), xv3 = uh(xr.w);
                s0 = fd2(xp[0][0], xv0, s0);
                s1 = fd2(xp[1][0], xv0, s1);
                s2 = fd2(xp[2][0], xv0, s2);
                s3 = fd2(xp[3][0], xv0, s3);
                s0 = fd2(xp[0][1], xv1, s0);
                s1 = fd2(xp[1][1], xv1, s1);
                s2 = fd2(xp[2][1], xv1, s2);
                s3 = fd2(xp[3][1], xv1, s3);
                s0 = fd2(xp[0][2], xv2, s0);
                s1 = fd2(xp[1][2], xv2, s1);
                s2 = fd2(xp[2][2], xv2, s2);
                s3 = fd2(xp[3][2], xv2, s3);
                s0 = fd2(xp[0][3], xv3, s0);
                s1 = fd2(xp[1][3], xv3, s1);
                s2 = fd2(xp[2][3], xv3, s2);
                s3 = fd2(xp[3][3], xv3, s3);
            }
            // FC lanes: s0 = wfc.h_{t-1} + b_fc = out[t-1] (delayed store)
            if ((ch | tt) != 0) { if (isFC) op[-kA] = s0; }
            // activations (scales pre-folded into weights/biases)
            const float iv = sigf(s0);
            const float fv = sigf(s1);
            const float gv = fmaf(2.0f, sigf(s2), -1.0f);
            const float ov = sigf(s3);
            // state update — fully in-lane, no cross-lane exchange
            c = fmaf(fv, c, iv * gv);
            const float tc = fmaf(2.0f, sigf(-kL2E2 * c), -1.0f);
            h = ov * tc;
            // packed h broadcast: Q = (h_r, h_{r+dir}); one DPP rotate = two h values
            const float hn1 = ror16f1(h);
            const uint32_t Q = pkrtz(h, hn1);
            hrp[0] = Q;
            hrp[1] = ror16u<2>(Q);
            hrp[2] = ror16u<4>(Q);
            hrp[3] = ror16u<6>(Q);
            hrp[4] = ror16u<8>(Q);
            hrp[5] = ror16u<10>(Q);
            hrp[6] = ror16u<12>(Q);
            hrp[7] = ror16u<14>(Q);
            if (tt + 1 < kTC) xr = xrn;
            op += kA;
        }
        if (ch + 1 < kNCH) {   // late LDS write of prefetched chunk + fence
            const int nb = cb ^ 1;
            uint2 u;
            u.x = pkrtz(rv0.x, rv0.y); u.y = pkrtz(rv0.z, rv0.w);
            *(uint2*)&xs[nb][reg + 2 * r] = u;
            u.x = pkrtz(rv1.x, rv1.y); u.y = pkrtz(rv1.z, rv1.w);
            *(uint2*)&xs[nb][reg + 32 + 2 * r] = u;
            asm volatile("s_waitcnt lgkmcnt(0)" ::: "memory");
            __builtin_amdgcn_sched_barrier(0);
            xr = *(const uint4*)&xs[nb][reg];
            cb = nb;
        }
    }

    {   // epilogue: out[T-1] = wfc . h_{T-1} + b_fc (full 8-pair h-dot)
        float s0 = bs[0];
#pragma unroll
        for (int jj = 0; jj < 8; ++jj)
            s0 = fd2(wp[0][jj], uh(hrp[jj]), s0);
        if (isFC) op[-kA] = s0;
    }
    if (!isFC) {   // hn, cn (fp32 master state), concatenated after out
        float* hn = out + (size_t)kB * kT * kA;
        hn[(size_t)b * kH + r] = h;
        hn[(size_t)kB * kH + (size_t)b * kH + r] = c;
    }
}

}  // namespace

extern "C" void kernel_launch(void* const* d_in, const int* in_sizes, int n_in,
                              void* d_out, int out_size, void* d_ws, size_t ws_size,
                              hipStream_t stream) {
    (void)in_sizes; (void)n_in; (void)d_ws; (void)ws_size; (void)out_size;
    const float* x    = (const float*)d_in[0];
    const float* W_ih = (const float*)d_in[1];
    const float* W_hh = (const float*)d_in[2];
    const float* b_ih = (const float*)d_in[3];
    const float* b_hh = (const float*)d_in[4];
    const float* W_fc = (const float*)d_in[5];
    const float* b_fc = (const float*)d_in[6];
    float* out = (float*)d_out;
    hipLaunchKernelGGL(lstm_fused_kernel, dim3(kB / 16), dim3(256), 0, stream,
                       x, W_ih, W_hh, b_ih, b_hh, W_fc, b_fc, out);
}

// Round 15
// 246.741 us; speedup vs baseline: 1.4394x; 1.0757x over previous
//
#include <hip/hip_runtime.h>
#include <cstddef>
#include <cstdint>

namespace {

typedef __fp16 h2v __attribute__((ext_vector_type(2)));

constexpr int kB = 4096, kT = 1024, kI = 8, kH = 12, kA = 4;
constexpr int kTC  = 32;               // timesteps per staged chunk (r11-proven)
constexpr int kNCH = kT / kTC;         // 32 chunks
constexpr int kXRegU = 132;            // 128 payload uints + 4 pad per element region
constexpr int kBlkU  = 16 * kXRegU;    // 16 elements per block

constexpr float kL2E  = 1.442695041f;   // log2(e)
constexpr float kL2E2 = 2.885390082f;   // 2*log2(e)

template<int N>
__device__ __forceinline__ uint32_t ror16u(uint32_t v) {
    return (uint32_t)__builtin_amdgcn_mov_dpp((int)v, 0x120 + N, 0xF, 0xF, false);
}
__device__ __forceinline__ float ror16f1(float v) {
    return __int_as_float(__builtin_amdgcn_mov_dpp(__float_as_int(v), 0x121, 0xF, 0xF, false));
}
__device__ __forceinline__ uint32_t pkrtz(float lo, float hi) {
    return __builtin_bit_cast(uint32_t, __builtin_amdgcn_cvt_pkrtz(lo, hi));
}
__device__ __forceinline__ h2v uh(uint32_t u) { return __builtin_bit_cast(h2v, u); }
__device__ __forceinline__ float fd2(h2v w, h2v v, float acc) {
    return __builtin_amdgcn_fdot2(w, v, acc, false);
}
__device__ __forceinline__ float sigf(float s) {   // rcp(1+exp2(s)), scale pre-folded
    return __builtin_amdgcn_rcpf(1.0f + __builtin_amdgcn_exp2f(s));
}

__global__
__attribute__((amdgpu_flat_work_group_size(256, 256), amdgpu_waves_per_eu(1, 1)))
void lstm_fused_kernel(const float* __restrict__ x,
                       const float* __restrict__ W_ih,
                       const float* __restrict__ W_hh,
                       const float* __restrict__ b_ih,
                       const float* __restrict__ b_hh,
                       const float* __restrict__ W_fc,
                       const float* __restrict__ b_fc,
                       float* __restrict__ out) {
    __shared__ uint32_t xs[2][kBlkU];   // staged x (f16 pairs), double-buffered, wave-private

    const int tid = threadIdx.x;
    const int wv  = tid >> 6;           // wave in block
    const int l64 = tid & 63;           // lane in wave
    const int grp = l64 >> 4;           // 16-lane group == DPP row == element
    const int r   = l64 & 15;           // unit index within element (12..15 = FC rows)
    const int ei  = wv * 4 + grp;       // element index within block
    const int b   = blockIdx.x * 16 + ei;
    const bool isFC = (r >= kH);
    const int a   = isFC ? (r - kH) : 0;

    // DPP row_ror direction probe (r5..r11-proven)
    const int probe = __builtin_amdgcn_mov_dpp(r, 0x121, 0xF, 0xF, false);
    const int dir   = (probe - r) & 15;

    // ---- packed f16 weights, all 4 gates per lane; h-cols pre-rotated & paired ----
    h2v wp[4][8], xp[4][4];
    float bs[4];
    if (!isFC) {
#pragma unroll
        for (int g = 0; g < 4; ++g) {              // PyTorch gate order i,f,g,o
            const int row = g * kH + r;
            const float scl = (g == 2) ? -kL2E2 : -kL2E;   // tanh row gets 2*log2e
#pragma unroll
            for (int jj = 0; jj < 8; ++jj) {
                const int c0 = (r + dir * 2 * jj) & 15;
                const int c1 = (c0 + dir) & 15;
                const float u0 = (c0 < kH) ? W_hh[row * kH + c0] : 0.0f;
                const float u1 = (c1 < kH) ? W_hh[row * kH + c1] : 0.0f;
                wp[g][jj] = h2v{(__fp16)(scl * u0), (__fp16)(scl * u1)};
            }
#pragma unroll
            for (int i2 = 0; i2 < 4; ++i2)
                xp[g][i2] = h2v{(__fp16)(scl * W_ih[row * kI + 2 * i2]),
                                (__fp16)(scl * W_ih[row * kI + 2 * i2 + 1])};
            bs[g] = scl * (b_ih[row] + b_hh[row]);
        }
    } else {   // FC lane: gate0 = W_fc row (unscaled); gates 1-3 all-zero
#pragma unroll
        for (int jj = 0; jj < 8; ++jj) {
            const int c0 = (r + dir * 2 * jj) & 15;
            const int c1 = (c0 + dir) & 15;
            const float u0 = (c0 < kH) ? W_fc[a * kH + c0] : 0.0f;
            const float u1 = (c1 < kH) ? W_fc[a * kH + c1] : 0.0f;
            wp[0][jj] = h2v{(__fp16)u0, (__fp16)u1};
            wp[1][jj] = h2v{(__fp16)0.f, (__fp16)0.f};
            wp[2][jj] = wp[1][jj];
            wp[3][jj] = wp[1][jj];
        }
#pragma unroll
        for (int i2 = 0; i2 < 4; ++i2) {
            xp[0][i2] = h2v{(__fp16)0.f, (__fp16)0.f};
            xp[1][i2] = xp[0][i2]; xp[2][i2] = xp[0][i2]; xp[3][i2] = xp[0][i2];
        }
        bs[0] = b_fc[a]; bs[1] = 0.0f; bs[2] = 0.0f; bs[3] = 0.0f;
        // f=sig(0)=0.5, g=0, o=0.5 -> c,h stay EXACTLY 0 on FC lanes (r11-proven)
    }

    // ---- x staging: each group stages its own element (f32 global -> f16 LDS) ----
    const float* xg = x + (size_t)b * (kT * kI);
    const int reg = ei * kXRegU;

    float4 rv0, rv1, rv2, rv3;
    {   // prologue: chunk 0 -> buffer 0
        const float4* gp = (const float4*)xg;
        rv0 = gp[r]; rv1 = gp[16 + r]; rv2 = gp[32 + r]; rv3 = gp[48 + r];
        uint2 u;
        u.x = pkrtz(rv0.x, rv0.y); u.y = pkrtz(rv0.z, rv0.w);
        *(uint2*)&xs[0][reg + 2 * r] = u;
        u.x = pkrtz(rv1.x, rv1.y); u.y = pkrtz(rv1.z, rv1.w);
        *(uint2*)&xs[0][reg + 32 + 2 * r] = u;
        u.x = pkrtz(rv2.x, rv2.y); u.y = pkrtz(rv2.z, rv2.w);
        *(uint2*)&xs[0][reg + 64 + 2 * r] = u;
        u.x = pkrtz(rv3.x, rv3.y); u.y = pkrtz(rv3.z, rv3.w);
        *(uint2*)&xs[0][reg + 96 + 2 * r] = u;
    }
    asm volatile("s_waitcnt lgkmcnt(0)" ::: "memory");
    __builtin_amdgcn_sched_barrier(0);

    float h = 0.0f, c = 0.0f;
    uint32_t hrp[8];
#pragma unroll
    for (int k = 0; k < 8; ++k) hrp[k] = 0u;

    uint4 xr = *(const uint4*)&xs[0][reg];   // step 0: 8 f16

    float* op = out + (size_t)b * (kT * kA) + a;

    int cb = 0;
#pragma unroll 1
    for (int ch = 0; ch < kNCH; ++ch) {
        if (ch + 1 < kNCH) {   // issue next chunk's global loads early
            const float4* gp = (const float4*)(xg + (size_t)(ch + 1) * (kTC * kI));
            rv0 = gp[r]; rv1 = gp[16 + r]; rv2 = gp[32 + r]; rv3 = gp[48 + r];
        }
#pragma unroll 2
        for (int tt = 0; tt < kTC; ++tt) {
            // prefetch next step's x FIRST (max slack before use)
            uint4 xrn;
            if (tt + 1 < kTC) xrn = *(const uint4*)&xs[cb][reg + (tt + 1) * 4];
            // 4 gate dots: 32 fdot2 over paired h + 16 over x (fp32 accum)
            float s0 = bs[0], s1 = bs[1], s2 = bs[2], s3 = bs[3];
#pragma unroll
            for (int jj = 0; jj < 8; ++jj) {
                const h2v hv = uh(hrp[jj]);
                s0 = fd2(wp[0][jj], hv, s0);
                s1 = fd2(wp[1][jj], hv, s1);
                s2 = fd2(wp[2][jj], hv, s2);
                s3 = fd2(wp[3][jj], hv, s3);
            }
            {
                const h2v xv0 = uh(xr.x), xv1 = uh(xr.y), xv2 = uh(xr.z), xv3 = uh(xr.w);
                s0 = fd2(xp[0][0], xv0, s0);
                s1 = fd2(xp[1][0], xv0, s1);
                s2 = fd2(xp[2][0], xv0, s2);
                s3 = fd2(xp[3][0], xv0, s3);
                s0 = fd2(xp[0][1], xv1, s0);
                s1 = fd2(xp[1][1], xv1, s1);
                s2 = fd2(xp[2][1], xv1, s2);
                s3 = fd2(xp[3][1], xv1, s3);
                s0 = fd2(xp[0][2], xv2, s0);
                s1 = fd2(xp[1][2], xv2, s1);
                s2 = fd2(xp[2][2], xv2, s2);
                s3 = fd2(xp[3][2], xv2, s3);
                s0 = fd2(xp[0][3], xv3, s0);
                s1 = fd2(xp[1][3], xv3, s1);
                s2 = fd2(xp[2][3], xv3, s2);
                s3 = fd2(xp[3][3], xv3, s3);
            }
            // FC lanes: s0 = wfc.h_{t-1} + b_fc = out[t-1] (delayed store)
            if ((ch | tt) != 0) { if (isFC) op[-kA] = s0; }
            // activations (scales pre-folded into weights/biases)
            const float iv = sigf(s0);
            const float fv = sigf(s1);
            const float gv = fmaf(2.0f, sigf(s2), -1.0f);
            const float ov = sigf(s3);
            // state update — fully in-lane, no cross-lane exchange
            c = fmaf(fv, c, iv * gv);
            const float tc = fmaf(2.0f, sigf(-kL2E2 * c), -1.0f);
            h = ov * tc;
            // packed h broadcast: Q = (h_r, h_{r+dir}); one DPP rotate = two h values
            const float hn1 = ror16f1(h);
            const uint32_t Q = pkrtz(h, hn1);
            hrp[0] = Q;
            hrp[1] = ror16u<2>(Q);
            hrp[2] = ror16u<4>(Q);
            hrp[3] = ror16u<6>(Q);
            hrp[4] = ror16u<8>(Q);
            hrp[5] = ror16u<10>(Q);
            hrp[6] = ror16u<12>(Q);
            hrp[7] = ror16u<14>(Q);
            if (tt + 1 < kTC) xr = xrn;
            op += kA;
        }
        if (ch + 1 < kNCH) {   // late LDS write of prefetched chunk + fence
            const int nb = cb ^ 1;
            uint2 u;
            u.x = pkrtz(rv0.x, rv0.y); u.y = pkrtz(rv0.z, rv0.w);
            *(uint2*)&xs[nb][reg + 2 * r] = u;
            u.x = pkrtz(rv1.x, rv1.y); u.y = pkrtz(rv1.z, rv1.w);
            *(uint2*)&xs[nb][reg + 32 + 2 * r] = u;
            u.x = pkrtz(rv2.x, rv2.y); u.y = pkrtz(rv2.z, rv2.w);
            *(uint2*)&xs[nb][reg + 64 + 2 * r] = u;
            u.x = pkrtz(rv3.x, rv3.y); u.y = pkrtz(rv3.z, rv3.w);
            *(uint2*)&xs[nb][reg + 96 + 2 * r] = u;
            asm volatile("s_waitcnt lgkmcnt(0)" ::: "memory");
            __builtin_amdgcn_sched_barrier(0);
            xr = *(const uint4*)&xs[nb][reg];
            cb = nb;
        }
    }

    {   // epilogue: out[T-1] = wfc . h_{T-1} + b_fc (full 8-pair h-dot)
        float s0 = bs[0];
#pragma unroll
        for (int jj = 0; jj < 8; ++jj)
            s0 = fd2(wp[0][jj], uh(hrp[jj]), s0);
        if (isFC) op[-kA] = s0;
    }
    if (!isFC) {   // hn, cn (fp32 master state), concatenated after out
        float* hn = out + (size_t)kB * kT * kA;
        hn[(size_t)b * kH + r] = h;
        hn[(size_t)kB * kH + (size_t)b * kH + r] = c;
    }
}

}  // namespace

extern "C" void kernel_launch(void* const* d_in, const int* in_sizes, int n_in,
                              void* d_out, int out_size, void* d_ws, size_t ws_size,
                              hipStream_t stream) {
    (void)in_sizes; (void)n_in; (void)d_ws; (void)ws_size; (void)out_size;
    const float* x    = (const float*)d_in[0];
    const float* W_ih = (const float*)d_in[1];
    const float* W_hh = (const float*)d_in[2];
    const float* b_ih = (const float*)d_in[3];
    const float* b_hh = (const float*)d_in[4];
    const float* W_fc = (const float*)d_in[5];
    const float* b_fc = (const float*)d_in[6];
    float* out = (float*)d_out;
    hipLaunchKernelGGL(lstm_fused_kernel, dim3(kB / 16), dim3(256), 0, stream,
                       x, W_ih, W_hh, b_ih, b_hh, W_fc, b_fc, out);
}

// Round 16
// 240.079 us; speedup vs baseline: 1.4793x; 1.0277x over previous
//
#include <hip/hip_runtime.h>
#include <cstddef>
#include <cstdint>

namespace {

typedef __fp16 h2v __attribute__((ext_vector_type(2)));

constexpr int kB = 4096, kT = 1024, kI = 8, kH = 12, kA = 4;
constexpr int kTC  = 32;               // timesteps per staged chunk (r11-proven)
constexpr int kNCH = kT / kTC;         // 32 chunks
constexpr int kXRegU = 132;            // 128 payload uints + 4 pad per element region
constexpr int kBlkU  = 16 * kXRegU;    // 16 elements per block

constexpr float kL2E  = 1.442695041f;   // log2(e)
constexpr float kL2E2 = 2.885390082f;   // 2*log2(e)

template<int N>
__device__ __forceinline__ uint32_t ror16u(uint32_t v) {
    return (uint32_t)__builtin_amdgcn_mov_dpp((int)v, 0x120 + N, 0xF, 0xF, false);
}
__device__ __forceinline__ float ror16f1(float v) {
    return __int_as_float(__builtin_amdgcn_mov_dpp(__float_as_int(v), 0x121, 0xF, 0xF, false));
}
__device__ __forceinline__ uint32_t pkrtz(float lo, float hi) {
    return __builtin_bit_cast(uint32_t, __builtin_amdgcn_cvt_pkrtz(lo, hi));
}
__device__ __forceinline__ h2v uh(uint32_t u) { return __builtin_bit_cast(h2v, u); }
__device__ __forceinline__ float fd2(h2v w, h2v v, float acc) {
    return __builtin_amdgcn_fdot2(w, v, acc, false);
}
__device__ __forceinline__ float sigf(float s) {   // rcp(1+exp2(s)), scale pre-folded
    return __builtin_amdgcn_rcpf(1.0f + __builtin_amdgcn_exp2f(s));
}

__global__
__attribute__((amdgpu_flat_work_group_size(256, 256), amdgpu_waves_per_eu(1, 1)))
void lstm_fused_kernel(const float* __restrict__ x,
                       const float* __restrict__ W_ih,
                       const float* __restrict__ W_hh,
                       const float* __restrict__ b_ih,
                       const float* __restrict__ b_hh,
                       const float* __restrict__ W_fc,
                       const float* __restrict__ b_fc,
                       float* __restrict__ out) {
    __shared__ uint32_t xs[2][kBlkU];   // staged x (f16 pairs), double-buffered, wave-private

    const int tid = threadIdx.x;
    const int wv  = tid >> 6;           // wave in block
    const int l64 = tid & 63;           // lane in wave
    const int grp = l64 >> 4;           // 16-lane group == DPP row == element
    const int r   = l64 & 15;           // unit index within element (12..15 = FC rows)
    const int ei  = wv * 4 + grp;       // element index within block
    const int b   = blockIdx.x * 16 + ei;
    const bool isFC = (r >= kH);
    const int a   = isFC ? (r - kH) : 0;

    // DPP row_ror direction probe (r5..r11-proven)
    const int probe = __builtin_amdgcn_mov_dpp(r, 0x121, 0xF, 0xF, false);
    const int dir   = (probe - r) & 15;

    // ---- packed f16 weights, all 4 gates per lane; h-cols pre-rotated & paired ----
    h2v wp[4][8], xp[4][4];
    float bs[4];
    if (!isFC) {
#pragma unroll
        for (int g = 0; g < 4; ++g) {              // PyTorch gate order i,f,g,o
            const int row = g * kH + r;
            const float scl = (g == 2) ? -kL2E2 : -kL2E;   // tanh row gets 2*log2e
#pragma unroll
            for (int jj = 0; jj < 8; ++jj) {
                const int c0 = (r + dir * 2 * jj) & 15;
                const int c1 = (c0 + dir) & 15;
                const float u0 = (c0 < kH) ? W_hh[row * kH + c0] : 0.0f;
                const float u1 = (c1 < kH) ? W_hh[row * kH + c1] : 0.0f;
                wp[g][jj] = h2v{(__fp16)(scl * u0), (__fp16)(scl * u1)};
            }
#pragma unroll
            for (int i2 = 0; i2 < 4; ++i2)
                xp[g][i2] = h2v{(__fp16)(scl * W_ih[row * kI + 2 * i2]),
                                (__fp16)(scl * W_ih[row * kI + 2 * i2 + 1])};
            bs[g] = scl * (b_ih[row] + b_hh[row]);
        }
    } else {   // FC lane: gate0 = W_fc row (unscaled); gates 1-3 all-zero
#pragma unroll
        for (int jj = 0; jj < 8; ++jj) {
            const int c0 = (r + dir * 2 * jj) & 15;
            const int c1 = (c0 + dir) & 15;
            const float u0 = (c0 < kH) ? W_fc[a * kH + c0] : 0.0f;
            const float u1 = (c1 < kH) ? W_fc[a * kH + c1] : 0.0f;
            wp[0][jj] = h2v{(__fp16)u0, (__fp16)u1};
            wp[1][jj] = h2v{(__fp16)0.f, (__fp16)0.f};
            wp[2][jj] = wp[1][jj];
            wp[3][jj] = wp[1][jj];
        }
#pragma unroll
        for (int i2 = 0; i2 < 4; ++i2) {
            xp[0][i2] = h2v{(__fp16)0.f, (__fp16)0.f};
            xp[1][i2] = xp[0][i2]; xp[2][i2] = xp[0][i2]; xp[3][i2] = xp[0][i2];
        }
        bs[0] = b_fc[a]; bs[1] = 0.0f; bs[2] = 0.0f; bs[3] = 0.0f;
        // f=sig(0)=0.5, g=0, o=0.5 -> c,h stay EXACTLY 0 on FC lanes (r11-proven)
    }

    // ---- x staging: each group stages its own element (f32 global -> f16 LDS) ----
    const float* xg = x + (size_t)b * (kT * kI);
    const int reg = ei * kXRegU;

    float4 rv0, rv1, rv2, rv3;
    {   // prologue: chunk 0 -> buffer 0
        const float4* gp = (const float4*)xg;
        rv0 = gp[r]; rv1 = gp[16 + r]; rv2 = gp[32 + r]; rv3 = gp[48 + r];
        uint2 u;
        u.x = pkrtz(rv0.x, rv0.y); u.y = pkrtz(rv0.z, rv0.w);
        *(uint2*)&xs[0][reg + 2 * r] = u;
        u.x = pkrtz(rv1.x, rv1.y); u.y = pkrtz(rv1.z, rv1.w);
        *(uint2*)&xs[0][reg + 32 + 2 * r] = u;
        u.x = pkrtz(rv2.x, rv2.y); u.y = pkrtz(rv2.z, rv2.w);
        *(uint2*)&xs[0][reg + 64 + 2 * r] = u;
        u.x = pkrtz(rv3.x, rv3.y); u.y = pkrtz(rv3.z, rv3.w);
        *(uint2*)&xs[0][reg + 96 + 2 * r] = u;
    }
    asm volatile("s_waitcnt lgkmcnt(0)" ::: "memory");
    __builtin_amdgcn_sched_barrier(0);

    float h = 0.0f, c = 0.0f;
    uint32_t hrp[8];
#pragma unroll
    for (int k = 0; k < 8; ++k) hrp[k] = 0u;

    uint4 xr = *(const uint4*)&xs[0][reg];   // step 0: 8 f16

    float* op = out + (size_t)b * (kT * kA) + a;

    int cb = 0;
#pragma unroll 1
    for (int ch = 0; ch < kNCH; ++ch) {
        if (ch + 1 < kNCH) {   // issue next chunk's global loads early
            const float4* gp = (const float4*)(xg + (size_t)(ch + 1) * (kTC * kI));
            rv0 = gp[r]; rv1 = gp[16 + r]; rv2 = gp[32 + r]; rv3 = gp[48 + r];
        }
#pragma unroll
        for (int tt = 0; tt < kTC; ++tt) {
            // prefetch next step's x FIRST (max slack before use)
            uint4 xrn;
            if (tt + 1 < kTC) xrn = *(const uint4*)&xs[cb][reg + (tt + 1) * 4];
            // 4 gate dots: 32 fdot2 over paired h + 16 over x (fp32 accum)
            float s0 = bs[0], s1 = bs[1], s2 = bs[2], s3 = bs[3];
#pragma unroll
            for (int jj = 0; jj < 8; ++jj) {
                const h2v hv = uh(hrp[jj]);
                s0 = fd2(wp[0][jj], hv, s0);
                s1 = fd2(wp[1][jj], hv, s1);
                s2 = fd2(wp[2][jj], hv, s2);
                s3 = fd2(wp[3][jj], hv, s3);
            }
            {
                const h2v xv0 = uh(xr.x), xv1 = uh(xr.y), xv2 = uh(xr.z), xv3 = uh(xr.w);
                s0 = fd2(xp[0][0], xv0, s0);
                s1 = fd2(xp[1][0], xv0, s1);
                s2 = fd2(xp[2][0], xv0, s2);
                s3 = fd2(xp[3][0], xv0, s3);
                s0 = fd2(xp[0][1], xv1, s0);
                s1 = fd2(xp[1][1], xv1, s1);
                s2 = fd2(xp[2][1], xv1, s2);
                s3 = fd2(xp[3][1], xv1, s3);
                s0 = fd2(xp[0][2], xv2, s0);
                s1 = fd2(xp[1][2], xv2, s1);
                s2 = fd2(xp[2][2], xv2, s2);
                s3 = fd2(xp[3][2], xv2, s3);
                s0 = fd2(xp[0][3], xv3, s0);
                s1 = fd2(xp[1][3], xv3, s1);
                s2 = fd2(xp[2][3], xv3, s2);
                s3 = fd2(xp[3][3], xv3, s3);
            }
            // FC lanes: s0 = wfc.h_{t-1} + b_fc = out[t-1] (delayed store)
            if ((ch | tt) != 0) { if (isFC) op[-kA] = s0; }
            // activations: paired reciprocals (4 rcp -> 2), scales pre-folded
            const float e0 = __builtin_amdgcn_exp2f(s0);
            const float e1 = __builtin_amdgcn_exp2f(s1);
            const float e2 = __builtin_amdgcn_exp2f(s2);
            const float e3 = __builtin_amdgcn_exp2f(s3);
            const float p0 = 1.0f + e0, p1 = 1.0f + e1;
            const float p2 = 1.0f + e2, p3 = 1.0f + e3;
            const float R01 = __builtin_amdgcn_rcpf(p0 * p1);
            const float R23 = __builtin_amdgcn_rcpf(p2 * p3);
            const float iv = p1 * R01;                      // 1/p0
            const float fv = p0 * R01;                      // 1/p1
            const float gv = fmaf(p3 + p3, R23, -1.0f);     // 2/p2 - 1
            const float ov = p2 * R23;                      // 1/p3
            // state update — fully in-lane, no cross-lane exchange
            c = fmaf(fv, c, iv * gv);
            const float tc = fmaf(2.0f, sigf(-kL2E2 * c), -1.0f);
            h = ov * tc;
            // packed h broadcast: Q = (h_r, h_{r+dir}); one DPP rotate = two h values
            const float hn1 = ror16f1(h);
            const uint32_t Q = pkrtz(h, hn1);
            hrp[0] = Q;
            hrp[1] = ror16u<2>(Q);
            hrp[2] = ror16u<4>(Q);
            hrp[3] = ror16u<6>(Q);
            hrp[4] = ror16u<8>(Q);
            hrp[5] = ror16u<10>(Q);
            hrp[6] = ror16u<12>(Q);
            hrp[7] = ror16u<14>(Q);
            if (tt + 1 < kTC) xr = xrn;
            op += kA;
        }
        if (ch + 1 < kNCH) {   // late LDS write of prefetched chunk + fence
            const int nb = cb ^ 1;
            uint2 u;
            u.x = pkrtz(rv0.x, rv0.y); u.y = pkrtz(rv0.z, rv0.w);
            *(uint2*)&xs[nb][reg + 2 * r] = u;
            u.x = pkrtz(rv1.x, rv1.y); u.y = pkrtz(rv1.z, rv1.w);
            *(uint2*)&xs[nb][reg + 32 + 2 * r] = u;
            u.x = pkrtz(rv2.x, rv2.y); u.y = pkrtz(rv2.z, rv2.w);
            *(uint2*)&xs[nb][reg + 64 + 2 * r] = u;
            u.x = pkrtz(rv3.x, rv3.y); u.y = pkrtz(rv3.z, rv3.w);
            *(uint2*)&xs[nb][reg + 96 + 2 * r] = u;
            asm volatile("s_waitcnt lgkmcnt(0)" ::: "memory");
            __builtin_amdgcn_sched_barrier(0);
            xr = *(const uint4*)&xs[nb][reg];
            cb = nb;
        }
    }

    {   // epilogue: out[T-1] = wfc . h_{T-1} + b_fc (full 8-pair h-dot)
        float s0 = bs[0];
#pragma unroll
        for (int jj = 0; jj < 8; ++jj)
            s0 = fd2(wp[0][jj], uh(hrp[jj]), s0);
        if (isFC) op[-kA] = s0;
    }
    if (!isFC) {   // hn, cn (fp32 master state), concatenated after out
        float* hn = out + (size_t)kB * kT * kA;
        hn[(size_t)b * kH + r] = h;
        hn[(size_t)kB * kH + (size_t)b * kH + r] = c;
    }
}

}  // namespace

extern "C" void kernel_launch(void* const* d_in, const int* in_sizes, int n_in,
                              void* d_out, int out_size, void* d_ws, size_t ws_size,
                              hipStream_t stream) {
    (void)in_sizes; (void)n_in; (void)d_ws; (void)ws_size; (void)out_size;
    const float* x    = (const float*)d_in[0];
    const float* W_ih = (const float*)d_in[1];
    const float* W_hh = (const float*)d_in[2];
    const float* b_ih = (const float*)d_in[3];
    const float* b_hh = (const float*)d_in[4];
    const float* W_fc = (const float*)d_in[5];
    const float* b_fc = (const float*)d_in[6];
    float* out = (float*)d_out;
    hipLaunchKernelGGL(lstm_fused_kernel, dim3(kB / 16), dim3(256), 0, stream,
                       x, W_ih, W_hh, b_ih, b_hh, W_fc, b_fc, out);
}